// Round 1
// baseline (185.567 us; speedup 1.0000x reference)
//
#include <hip/hip_runtime.h>

constexpr int Bc = 2, Lc = 2048, Sc = 2048, Hc = 16, Ec = 64, Dc = 64;
constexpr int STILE = 64;   // S-tile per iteration
constexpr int LBLK  = 64;   // L rows per workgroup (4 waves x 16)
constexpr int KSTR  = 72;   // K-tile row stride in bf16 elems (144B, 16B-mult)
constexpr int VSTR  = 88;   // V^T row stride (176B)
constexpr int PSTR  = 88;   // P-bounce row stride (176B)

typedef float          f32x4  __attribute__((ext_vector_type(4)));
typedef __bf16         bf16x8 __attribute__((ext_vector_type(8)));
typedef unsigned short u16x8  __attribute__((ext_vector_type(8)));
typedef unsigned short u16x4  __attribute__((ext_vector_type(4)));

static __device__ __forceinline__ unsigned short f2bf(float f) {
    unsigned u = __builtin_bit_cast(unsigned, f);
    u += 0x7fffu + ((u >> 16) & 1u);          // round-to-nearest-even
    return (unsigned short)(u >> 16);
}

__global__ __launch_bounds__(256) void dual_attn_kernel(
    const float* __restrict__ q1, const float* __restrict__ k1,
    const float* __restrict__ v1, const float* __restrict__ q2,
    const float* __restrict__ k2, float* __restrict__ out)
{
    __shared__ unsigned short k1t[STILE * KSTR];     // 9216 B
    __shared__ unsigned short k2t[STILE * KSTR];     // 9216 B
    __shared__ unsigned short vtt[Dc * VSTR];        // 11264 B (V transposed)
    __shared__ unsigned short pt [4 * 16 * PSTR];    // 11264 B (per-wave P bounce)

    const int blk  = blockIdx.x;
    const int lblk = blk & ((Lc / LBLK) - 1);        // 32 L-blocks
    const int bh   = blk >> 5;
    const int b    = bh >> 4;
    const int h    = bh & (Hc - 1);

    const int tid  = threadIdx.x;
    const int w    = tid >> 6;                       // wave 0..3
    const int lane = tid & 63;
    const int lr   = lane & 15;
    const int lg   = lane >> 4;

    // ---- Q fragments in registers (A-frag: row = lane&15, k = 8*(lane>>4)+j) ----
    const int    qrow  = lblk * LBLK + w * 16 + lr;
    const size_t qbase = ((size_t)(b * Lc + qrow) * Hc + h) * Ec;
    bf16x8 a1[2], a2[2];
    for (int es = 0; es < 2; ++es) {
        u16x8 t1, t2;
        for (int j = 0; j < 8; ++j) {
            t1[j] = f2bf(q1[qbase + es * 32 + lg * 8 + j]);
            t2[j] = f2bf(q2[qbase + es * 32 + lg * 8 + j]);
        }
        a1[es] = __builtin_bit_cast(bf16x8, t1);
        a2[es] = __builtin_bit_cast(bf16x8, t2);
    }

    f32x4 acc[4];
    for (int i = 0; i < 4; ++i) acc[i] = (f32x4){0.f, 0.f, 0.f, 0.f};

    constexpr float CT = 0.25f;    // 2 * (1/sqrt(64))  for tanh's e^{2x}
    constexpr float CS = -0.125f;  // -(1/sqrt(64))     for sigmoid's e^{-y}

    for (int s0 = 0; s0 < Sc; s0 += STILE) {
        // ---- stage K1, K2 (row-major) and V1 (transposed) as bf16 ----
        for (int it = 0; it < 4; ++it) {
            int idx = tid + it * 256;                // 0..1023
            int sr  = idx >> 4;                      // 0..63 (s row)
            int c4  = (idx & 15) << 2;               // 0..60 (e or d)
            size_t gk = ((size_t)(b * Sc + s0 + sr) * Hc + h) * Ec + c4;
            float4 x1 = *reinterpret_cast<const float4*>(k1 + gk);
            float4 x2 = *reinterpret_cast<const float4*>(k2 + gk);
            float4 xv = *reinterpret_cast<const float4*>(v1 + gk);  // Dc==Ec, same layout
            u16x4 o1, o2;
            o1[0]=f2bf(x1.x); o1[1]=f2bf(x1.y); o1[2]=f2bf(x1.z); o1[3]=f2bf(x1.w);
            o2[0]=f2bf(x2.x); o2[1]=f2bf(x2.y); o2[2]=f2bf(x2.z); o2[3]=f2bf(x2.w);
            *reinterpret_cast<u16x4*>(&k1t[sr * KSTR + c4]) = o1;
            *reinterpret_cast<u16x4*>(&k2t[sr * KSTR + c4]) = o2;
            vtt[(c4 + 0) * VSTR + sr] = f2bf(xv.x);
            vtt[(c4 + 1) * VSTR + sr] = f2bf(xv.y);
            vtt[(c4 + 2) * VSTR + sr] = f2bf(xv.z);
            vtt[(c4 + 3) * VSTR + sr] = f2bf(xv.w);
        }
        __syncthreads();

        // ---- scores (2 MFMAs/ct each for S1,S2) + activation -> P bounce ----
        for (int ct = 0; ct < 4; ++ct) {
            f32x4 s1 = {0.f,0.f,0.f,0.f}, s2 = {0.f,0.f,0.f,0.f};
            for (int es = 0; es < 2; ++es) {
                bf16x8 b1 = __builtin_bit_cast(bf16x8,
                    *reinterpret_cast<const u16x8*>(&k1t[(ct*16 + lr) * KSTR + es*32 + lg*8]));
                bf16x8 b2 = __builtin_bit_cast(bf16x8,
                    *reinterpret_cast<const u16x8*>(&k2t[(ct*16 + lr) * KSTR + es*32 + lg*8]));
                s1 = __builtin_amdgcn_mfma_f32_16x16x32_bf16(a1[es], b1, s1, 0, 0, 0);
                s2 = __builtin_amdgcn_mfma_f32_16x16x32_bf16(a2[es], b2, s2, 0, 0, 0);
            }
            for (int i = 0; i < 4; ++i) {
                float xa = fminf(fmaxf(s1[i] * CT, -30.f), 30.f);
                float xb = fminf(fmaxf(s2[i] * CS, -30.f), 30.f);
                float t  = __expf(xa);                 // e^{2*scale*s1}
                float u  = __expf(xb);                 // e^{-scale*s2}
                float p  = (t - 1.f) * __builtin_amdgcn_rcpf((t + 1.f) * (1.f + u));
                // C/D layout: row = lg*4+i, col = lr
                pt[(w*16 + lg*4 + i) * PSTR + ct*16 + lr] = f2bf(p);
            }
        }
        // wave-local: P writes -> P reads (same wave only; no cross-wave use)
        asm volatile("s_waitcnt lgkmcnt(0)" ::: "memory");

        // ---- PV: out_tile += P[16x64] * V[64x64] ----
        for (int ks = 0; ks < 2; ++ks) {
            bf16x8 pa = __builtin_bit_cast(bf16x8,
                *reinterpret_cast<const u16x8*>(&pt[(w*16 + lr) * PSTR + ks*32 + lg*8]));
            for (int dt = 0; dt < 4; ++dt) {
                bf16x8 vb = __builtin_bit_cast(bf16x8,
                    *reinterpret_cast<const u16x8*>(&vtt[(dt*16 + lr) * VSTR + ks*32 + lg*8]));
                acc[dt] = __builtin_amdgcn_mfma_f32_16x16x32_bf16(pa, vb, acc[dt], 0, 0, 0);
            }
        }
        __syncthreads();   // protect LDS tiles before next staging
    }

    // ---- epilogue: C/D layout -> (B,L,H,D) fp32 ----
    const int orow = lblk * LBLK + w * 16;
    for (int dt = 0; dt < 4; ++dt)
        for (int i = 0; i < 4; ++i) {
            int l = orow + lg * 4 + i;
            out[((size_t)(b * Lc + l) * Hc + h) * Dc + dt * 16 + lr] = acc[dt][i];
        }
}

extern "C" void kernel_launch(void* const* d_in, const int* in_sizes, int n_in,
                              void* d_out, int out_size, void* d_ws, size_t ws_size,
                              hipStream_t stream) {
    const float* q1 = (const float*)d_in[0];
    const float* k1 = (const float*)d_in[1];
    const float* v1 = (const float*)d_in[2];
    const float* q2 = (const float*)d_in[3];
    const float* k2 = (const float*)d_in[4];
    // d_in[5] (v2) and d_in[6] (attn_mask) are unused by the reference forward.
    float* out = (float*)d_out;

    dim3 grid(Bc * Hc * (Lc / LBLK));   // 1024 workgroups
    dim3 block(256);
    dual_attn_kernel<<<grid, block, 0, stream>>>(q1, k1, v1, q2, k2, out);
}

// Round 2
// 117.420 us; speedup vs baseline: 1.5804x; 1.5804x over previous
//
#include <hip/hip_runtime.h>

constexpr int Bc = 2, Lc = 2048, Sc = 2048, Hc = 16, Ec = 64, Dc = 64;
constexpr int TILES = Sc / 64;            // 32 S-tiles
constexpr int NBH   = Bc * Hc;            // 32
constexpr size_t TILE_ELEMS = 4096;       // 64x64 bf16 tile
constexpr size_t ARR_ELEMS  = (size_t)NBH * TILES * TILE_ELEMS;   // 4,194,304
constexpr size_t WS_NEED    = ARR_ELEMS * 2 * 3;                  // 25,165,824 B

typedef float          f32x4  __attribute__((ext_vector_type(4)));
typedef __bf16         bf16x8 __attribute__((ext_vector_type(8)));
typedef unsigned short u16x8  __attribute__((ext_vector_type(8)));
typedef unsigned short u16x4  __attribute__((ext_vector_type(4)));
typedef unsigned int   u32x4  __attribute__((ext_vector_type(4)));

static __device__ __forceinline__ unsigned cvtpk(float lo, float hi) {
    unsigned r;
    asm("v_cvt_pk_bf16_f32 %0, %1, %2" : "=v"(r) : "v"(lo), "v"(hi));
    return r;
}

static __device__ __forceinline__ void gl2lds16(const void* g, void* l) {
    __builtin_amdgcn_global_load_lds(
        (const __attribute__((address_space(1))) unsigned int*)g,
        (__attribute__((address_space(3))) unsigned int*)l, 16, 0, 0);
}

static __device__ __forceinline__ float fexp2(float x) {
#if __has_builtin(__builtin_amdgcn_exp2f)
    return __builtin_amdgcn_exp2f(x);
#else
    return exp2f(x);
#endif
}

// ---------------------------------------------------------------------------
// Pre-pass: fp32 K1,K2,V1 -> bf16, blocked per (bh, stile), pre-XOR-swizzled.
// Tile image (8KB): 16B unit at pos16 = row*8 + (col16 ^ (row&7)); K rows = s,
// V rows = d (transposed via LDS).
// ---------------------------------------------------------------------------
__global__ __launch_bounds__(256) void prepass_kernel(
    const float* __restrict__ k1, const float* __restrict__ k2,
    const float* __restrict__ v1,
    unsigned short* __restrict__ k1b, unsigned short* __restrict__ k2b,
    unsigned short* __restrict__ vb)
{
    __shared__ unsigned short vt[64 * 80];     // bf16 V tile, padded stride 160B

    const int blk = blockIdx.x;                // bh*32 + st
    const int st  = blk & 31;
    const int bh  = blk >> 5;
    const int b   = bh >> 4, h = bh & 15;
    const int s0  = st * 64;
    const size_t tileo = (size_t)blk * TILE_ELEMS;

    #pragma unroll
    for (int it = 0; it < 2; ++it) {
        int u  = threadIdx.x + it * 256;       // 0..511
        int s  = u >> 3, e8 = u & 7;
        size_t g = ((size_t)((b * Sc + s0 + s) * Hc + h)) * Ec + e8 * 8;

        float4 x0 = *reinterpret_cast<const float4*>(k1 + g);
        float4 x1 = *reinterpret_cast<const float4*>(k1 + g + 4);
        u32x4 o;
        o[0] = cvtpk(x0.x, x0.y); o[1] = cvtpk(x0.z, x0.w);
        o[2] = cvtpk(x1.x, x1.y); o[3] = cvtpk(x1.z, x1.w);
        *reinterpret_cast<u32x4*>(&k1b[tileo + (size_t)(s * 8 + (e8 ^ (s & 7))) * 8]) = o;

        x0 = *reinterpret_cast<const float4*>(k2 + g);
        x1 = *reinterpret_cast<const float4*>(k2 + g + 4);
        o[0] = cvtpk(x0.x, x0.y); o[1] = cvtpk(x0.z, x0.w);
        o[2] = cvtpk(x1.x, x1.y); o[3] = cvtpk(x1.z, x1.w);
        *reinterpret_cast<u32x4*>(&k2b[tileo + (size_t)(s * 8 + (e8 ^ (s & 7))) * 8]) = o;

        x0 = *reinterpret_cast<const float4*>(v1 + g);
        x1 = *reinterpret_cast<const float4*>(v1 + g + 4);
        o[0] = cvtpk(x0.x, x0.y); o[1] = cvtpk(x0.z, x0.w);
        o[2] = cvtpk(x1.x, x1.y); o[3] = cvtpk(x1.z, x1.w);
        *reinterpret_cast<u32x4*>(&vt[s * 80 + e8 * 8]) = o;   // row-major [s][d]
    }
    __syncthreads();

    #pragma unroll
    for (int it = 0; it < 2; ++it) {
        int u  = threadIdx.x + it * 256;
        int d  = u >> 3, sc8 = u & 7;
        u16x8 o;
        #pragma unroll
        for (int j = 0; j < 8; ++j) o[j] = vt[(sc8 * 8 + j) * 80 + d];  // gather column
        *reinterpret_cast<u16x8*>(&vb[tileo + (size_t)(d * 8 + (sc8 ^ (d & 7))) * 8]) = o;
    }
}

// ---------------------------------------------------------------------------
// Main fused kernel. Q pre-scaled (scale*log2e folded) so t=2^s1, u=2^s2.
// Swapped QK^T: mfma(K,Q) -> C rows = s, cols = q. P packed along s via
// cvt_pk into padded u32 bounce (stride 19), read back as PV A-fragments.
// ---------------------------------------------------------------------------
__global__ __launch_bounds__(256) void fused_kernel(
    const float* __restrict__ q1, const float* __restrict__ q2,
    const unsigned short* __restrict__ k1b, const unsigned short* __restrict__ k2b,
    const unsigned short* __restrict__ vb, float* __restrict__ out)
{
    __shared__ unsigned short k1t[4096];
    __shared__ unsigned short k2t[4096];
    __shared__ unsigned short vtt[4096];
    __shared__ unsigned int   ptb[4][608];     // per-wave P bounce, stride 19 u32

    const int orig    = blockIdx.x;
    const int logical = (orig & 7) * 128 + (orig >> 3);   // XCD-chunked swizzle
    const int lblk = logical & 31;
    const int bh   = logical >> 5;
    const int b    = bh >> 4, h = bh & 15;

    const int tid  = threadIdx.x;
    const int w    = tid >> 6;
    const int lane = tid & 63;
    const int lr   = lane & 15;
    const int lg   = lane >> 4;

    // Q fragments (B-operand: col=lane&15=q-row, k=8*lg+j=e), scale folded.
    constexpr float C1 = 0.36067376022224085f;    // 2*(1/8)*log2(e)
    constexpr float C2 = -0.18033688011112043f;   // -(1/8)*log2(e)
    const int    qrow  = lblk * 64 + w * 16 + lr;
    const size_t qbase = ((size_t)((b * Lc + qrow) * Hc + h)) * Ec;
    bf16x8 a1[2], a2[2];
    #pragma unroll
    for (int es = 0; es < 2; ++es) {
        const float* p1 = q1 + qbase + es * 32 + lg * 8;
        const float* p2 = q2 + qbase + es * 32 + lg * 8;
        float4 x0 = *reinterpret_cast<const float4*>(p1);
        float4 x1 = *reinterpret_cast<const float4*>(p1 + 4);
        u32x4 o;
        o[0] = cvtpk(x0.x * C1, x0.y * C1); o[1] = cvtpk(x0.z * C1, x0.w * C1);
        o[2] = cvtpk(x1.x * C1, x1.y * C1); o[3] = cvtpk(x1.z * C1, x1.w * C1);
        a1[es] = __builtin_bit_cast(bf16x8, o);
        x0 = *reinterpret_cast<const float4*>(p2);
        x1 = *reinterpret_cast<const float4*>(p2 + 4);
        o[0] = cvtpk(x0.x * C2, x0.y * C2); o[1] = cvtpk(x0.z * C2, x0.w * C2);
        o[2] = cvtpk(x1.x * C2, x1.y * C2); o[3] = cvtpk(x1.z * C2, x1.w * C2);
        a2[es] = __builtin_bit_cast(bf16x8, o);
    }

    f32x4 acc[4];
    #pragma unroll
    for (int i = 0; i < 4; ++i) acc[i] = (f32x4){0.f, 0.f, 0.f, 0.f};

    const unsigned short* k1g = k1b + (size_t)bh * TILES * TILE_ELEMS;
    const unsigned short* k2g = k2b + (size_t)bh * TILES * TILE_ELEMS;
    const unsigned short* vg  = vb  + (size_t)bh * TILES * TILE_ELEMS;
    unsigned int* ptw = &ptb[w][0];

    for (int st = 0; st < TILES; ++st) {
        const size_t tb = (size_t)st * TILE_ELEMS + tid * 8;
        gl2lds16(k1g + tb,        &k1t[tid * 8]);
        gl2lds16(k1g + tb + 2048, &k1t[2048 + tid * 8]);
        gl2lds16(k2g + tb,        &k2t[tid * 8]);
        gl2lds16(k2g + tb + 2048, &k2t[2048 + tid * 8]);
        gl2lds16(vg  + tb,        &vtt[tid * 8]);
        gl2lds16(vg  + tb + 2048, &vtt[2048 + tid * 8]);
        __syncthreads();

        // scores + activation -> packed P bounce
        #pragma unroll
        for (int ct = 0; ct < 4; ++ct) {
            f32x4 s1 = {0.f, 0.f, 0.f, 0.f}, s2 = {0.f, 0.f, 0.f, 0.f};
            #pragma unroll
            for (int es = 0; es < 2; ++es) {
                const int off = (ct * 16 + lr) * 64 + (((4 * es + lg) ^ (lr & 7)) * 8);
                bf16x8 kb1 = __builtin_bit_cast(bf16x8, *reinterpret_cast<const u16x8*>(&k1t[off]));
                bf16x8 kb2 = __builtin_bit_cast(bf16x8, *reinterpret_cast<const u16x8*>(&k2t[off]));
                s1 = __builtin_amdgcn_mfma_f32_16x16x32_bf16(kb1, a1[es], s1, 0, 0, 0);
                s2 = __builtin_amdgcn_mfma_f32_16x16x32_bf16(kb2, a2[es], s2, 0, 0, 0);
            }
            float p[4];
            #pragma unroll
            for (int i = 0; i < 4; ++i) {
                float t  = fexp2(s1[i]);          // e^{2*scale*score1}
                float uu = fexp2(s2[i]);          // e^{-scale*score2}
                p[i] = (t - 1.f) * __builtin_amdgcn_rcpf((t + 1.f) * (1.f + uu));
            }
            const int pb = (8 * ct + 2 * lg) * 19 + lr;
            ptw[pb]      = cvtpk(p[0], p[1]);
            ptw[pb + 19] = cvtpk(p[2], p[3]);
        }

        // PV: acc[dt] += P(16q x 64s) * V(64s x 64d)
        #pragma unroll
        for (int ks = 0; ks < 2; ++ks) {
            u32x4 pw;
            #pragma unroll
            for (int wd = 0; wd < 4; ++wd)
                pw[wd] = ptw[(16 * ks + 4 * lg + wd) * 19 + lr];
            bf16x8 pa = __builtin_bit_cast(bf16x8, pw);
            #pragma unroll
            for (int dt = 0; dt < 4; ++dt) {
                const int off = (dt * 16 + lr) * 64 + (((4 * ks + lg) ^ (lr & 7)) * 8);
                bf16x8 vf = __builtin_bit_cast(bf16x8, *reinterpret_cast<const u16x8*>(&vtt[off]));
                acc[dt] = __builtin_amdgcn_mfma_f32_16x16x32_bf16(pa, vf, acc[dt], 0, 0, 0);
            }
        }
        __syncthreads();
    }

    // epilogue: C/D layout (col=lane&15=d, row=lg*4+i=q) -> (B,L,H,D) fp32
    const int orow = lblk * 64 + w * 16;
    #pragma unroll
    for (int dt = 0; dt < 4; ++dt)
        #pragma unroll
        for (int i = 0; i < 4; ++i) {
            int l = orow + lg * 4 + i;
            out[((size_t)(b * Lc + l) * Hc + h) * Dc + dt * 16 + lr] = acc[dt][i];
        }
}

// ---------------------------------------------------------------------------
// Fallback (round-1 kernel, proven correct) if ws_size is too small.
// ---------------------------------------------------------------------------
static __device__ __forceinline__ unsigned short f2bf(float f) {
    unsigned u = __builtin_bit_cast(unsigned, f);
    u += 0x7fffu + ((u >> 16) & 1u);
    return (unsigned short)(u >> 16);
}

__global__ __launch_bounds__(256) void fallback_kernel(
    const float* __restrict__ q1, const float* __restrict__ k1,
    const float* __restrict__ v1, const float* __restrict__ q2,
    const float* __restrict__ k2, float* __restrict__ out)
{
    constexpr int KSTR = 72, VSTR = 88, PSTR = 88;
    __shared__ unsigned short k1t[64 * KSTR];
    __shared__ unsigned short k2t[64 * KSTR];
    __shared__ unsigned short vtt[64 * VSTR];
    __shared__ unsigned short pt [4 * 16 * PSTR];

    const int blk  = blockIdx.x;
    const int lblk = blk & 31;
    const int bh   = blk >> 5;
    const int b    = bh >> 4;
    const int h    = bh & 15;
    const int tid  = threadIdx.x;
    const int w    = tid >> 6;
    const int lane = tid & 63;
    const int lr   = lane & 15;
    const int lg   = lane >> 4;

    const int    qrow  = lblk * 64 + w * 16 + lr;
    const size_t qbase = ((size_t)(b * Lc + qrow) * Hc + h) * Ec;
    bf16x8 a1[2], a2[2];
    for (int es = 0; es < 2; ++es) {
        u16x8 t1, t2;
        for (int j = 0; j < 8; ++j) {
            t1[j] = f2bf(q1[qbase + es * 32 + lg * 8 + j]);
            t2[j] = f2bf(q2[qbase + es * 32 + lg * 8 + j]);
        }
        a1[es] = __builtin_bit_cast(bf16x8, t1);
        a2[es] = __builtin_bit_cast(bf16x8, t2);
    }
    f32x4 acc[4];
    for (int i = 0; i < 4; ++i) acc[i] = (f32x4){0.f, 0.f, 0.f, 0.f};
    constexpr float CT = 0.25f, CS = -0.125f;

    for (int s0 = 0; s0 < Sc; s0 += 64) {
        for (int it = 0; it < 4; ++it) {
            int idx = tid + it * 256;
            int sr  = idx >> 4;
            int c4  = (idx & 15) << 2;
            size_t gk = ((size_t)(b * Sc + s0 + sr) * Hc + h) * Ec + c4;
            float4 x1 = *reinterpret_cast<const float4*>(k1 + gk);
            float4 x2 = *reinterpret_cast<const float4*>(k2 + gk);
            float4 xv = *reinterpret_cast<const float4*>(v1 + gk);
            u16x4 o1, o2;
            o1[0]=f2bf(x1.x); o1[1]=f2bf(x1.y); o1[2]=f2bf(x1.z); o1[3]=f2bf(x1.w);
            o2[0]=f2bf(x2.x); o2[1]=f2bf(x2.y); o2[2]=f2bf(x2.z); o2[3]=f2bf(x2.w);
            *reinterpret_cast<u16x4*>(&k1t[sr * KSTR + c4]) = o1;
            *reinterpret_cast<u16x4*>(&k2t[sr * KSTR + c4]) = o2;
            vtt[(c4 + 0) * VSTR + sr] = f2bf(xv.x);
            vtt[(c4 + 1) * VSTR + sr] = f2bf(xv.y);
            vtt[(c4 + 2) * VSTR + sr] = f2bf(xv.z);
            vtt[(c4 + 3) * VSTR + sr] = f2bf(xv.w);
        }
        __syncthreads();
        for (int ct = 0; ct < 4; ++ct) {
            f32x4 s1 = {0.f,0.f,0.f,0.f}, s2 = {0.f,0.f,0.f,0.f};
            for (int es = 0; es < 2; ++es) {
                bf16x8 b1 = __builtin_bit_cast(bf16x8,
                    *reinterpret_cast<const u16x8*>(&k1t[(ct*16 + lr) * KSTR + es*32 + lg*8]));
                bf16x8 b2 = __builtin_bit_cast(bf16x8,
                    *reinterpret_cast<const u16x8*>(&k2t[(ct*16 + lr) * KSTR + es*32 + lg*8]));
                s1 = __builtin_amdgcn_mfma_f32_16x16x32_bf16(a1[es], b1, s1, 0, 0, 0);
                s2 = __builtin_amdgcn_mfma_f32_16x16x32_bf16(a2[es], b2, s2, 0, 0, 0);
            }
            for (int i = 0; i < 4; ++i) {
                float xa = fminf(fmaxf(s1[i] * CT, -30.f), 30.f);
                float xb = fminf(fmaxf(s2[i] * CS, -30.f), 30.f);
                float t  = __expf(xa);
                float u  = __expf(xb);
                float p  = (t - 1.f) * __builtin_amdgcn_rcpf((t + 1.f) * (1.f + u));
                pt[(w*16 + lg*4 + i) * PSTR + ct*16 + lr] = f2bf(p);
            }
        }
        asm volatile("s_waitcnt lgkmcnt(0)" ::: "memory");
        for (int ks = 0; ks < 2; ++ks) {
            bf16x8 pa = __builtin_bit_cast(bf16x8,
                *reinterpret_cast<const u16x8*>(&pt[(w*16 + lr) * PSTR + ks*32 + lg*8]));
            for (int dt = 0; dt < 4; ++dt) {
                bf16x8 vf = __builtin_bit_cast(bf16x8,
                    *reinterpret_cast<const u16x8*>(&vtt[(dt*16 + lr) * VSTR + ks*32 + lg*8]));
                acc[dt] = __builtin_amdgcn_mfma_f32_16x16x32_bf16(pa, vf, acc[dt], 0, 0, 0);
            }
        }
        __syncthreads();
    }
    const int orow = lblk * 64 + w * 16;
    for (int dt = 0; dt < 4; ++dt)
        for (int i = 0; i < 4; ++i) {
            int l = orow + lg * 4 + i;
            out[((size_t)(b * Lc + l) * Hc + h) * Dc + dt * 16 + lr] = acc[dt][i];
        }
}

extern "C" void kernel_launch(void* const* d_in, const int* in_sizes, int n_in,
                              void* d_out, int out_size, void* d_ws, size_t ws_size,
                              hipStream_t stream) {
    const float* q1 = (const float*)d_in[0];
    const float* k1 = (const float*)d_in[1];
    const float* v1 = (const float*)d_in[2];
    const float* q2 = (const float*)d_in[3];
    const float* k2 = (const float*)d_in[4];
    float* out = (float*)d_out;

    if (ws_size >= WS_NEED) {
        unsigned short* k1b = (unsigned short*)d_ws;
        unsigned short* k2b = k1b + ARR_ELEMS;
        unsigned short* vbp = k2b + ARR_ELEMS;
        prepass_kernel<<<dim3(NBH * TILES), dim3(256), 0, stream>>>(k1, k2, v1, k1b, k2b, vbp);
        fused_kernel<<<dim3(NBH * TILES), dim3(256), 0, stream>>>(q1, q2, k1b, k2b, vbp, out);
    } else {
        fallback_kernel<<<dim3(NBH * TILES), dim3(256), 0, stream>>>(q1, k1, v1, q2, k2, out);
    }
}

// Round 3
// 115.271 us; speedup vs baseline: 1.6098x; 1.0186x over previous
//
#include <hip/hip_runtime.h>

constexpr int Bc = 2, Lc = 2048, Sc = 2048, Hc = 16, Ec = 64, Dc = 64;
constexpr int TILES = Sc / 64;            // 32 S-tiles
constexpr int NBH   = Bc * Hc;            // 32
constexpr size_t TILE_ELEMS = 4096;       // 64x64 bf16 tile
constexpr size_t ARR_ELEMS  = (size_t)NBH * TILES * TILE_ELEMS;   // 4,194,304
constexpr size_t WS_NEED    = ARR_ELEMS * 2 * 3;                  // 25,165,824 B

typedef float          f32x4  __attribute__((ext_vector_type(4)));
typedef __bf16         bf16x8 __attribute__((ext_vector_type(8)));
typedef unsigned short u16x8  __attribute__((ext_vector_type(8)));
typedef unsigned short u16x4  __attribute__((ext_vector_type(4)));
typedef unsigned int   u32x4  __attribute__((ext_vector_type(4)));
typedef unsigned int   u32x2  __attribute__((ext_vector_type(2)));

static __device__ __forceinline__ unsigned cvtpk(float lo, float hi) {
    unsigned r;
    asm("v_cvt_pk_bf16_f32 %0, %1, %2" : "=v"(r) : "v"(lo), "v"(hi));
    return r;
}

static __device__ __forceinline__ void gl2lds16(const void* g, void* l) {
    __builtin_amdgcn_global_load_lds(
        (const __attribute__((address_space(1))) unsigned int*)g,
        (__attribute__((address_space(3))) unsigned int*)l, 16, 0, 0);
}

static __device__ __forceinline__ float fexp2(float x) {
#if __has_builtin(__builtin_amdgcn_exp2f)
    return __builtin_amdgcn_exp2f(x);
#else
    return exp2f(x);
#endif
}

// ---------------------------------------------------------------------------
// Pre-pass: fp32 K1,K2,V1 -> bf16 tiles per (bh, stile).
// K tiles pre-XOR-swizzled (16B unit at s*8 + (e8 ^ (s&7))) for LDS path.
// V tiles transposed [d][s] row-major, UNswizzled (read direct from L2).
// ---------------------------------------------------------------------------
__global__ __launch_bounds__(256) void prepass_kernel(
    const float* __restrict__ k1, const float* __restrict__ k2,
    const float* __restrict__ v1,
    unsigned short* __restrict__ k1b, unsigned short* __restrict__ k2b,
    unsigned short* __restrict__ vb)
{
    __shared__ unsigned short vt[64 * 80];     // bf16 V tile, padded stride

    const int blk = blockIdx.x;                // bh*32 + st
    const int st  = blk & 31;
    const int bh  = blk >> 5;
    const int b   = bh >> 4, h = bh & 15;
    const int s0  = st * 64;
    const size_t tileo = (size_t)blk * TILE_ELEMS;

    #pragma unroll
    for (int it = 0; it < 2; ++it) {
        int u  = threadIdx.x + it * 256;       // 0..511
        int s  = u >> 3, e8 = u & 7;
        size_t g = ((size_t)((b * Sc + s0 + s) * Hc + h)) * Ec + e8 * 8;

        float4 x0 = *reinterpret_cast<const float4*>(k1 + g);
        float4 x1 = *reinterpret_cast<const float4*>(k1 + g + 4);
        u32x4 o;
        o[0] = cvtpk(x0.x, x0.y); o[1] = cvtpk(x0.z, x0.w);
        o[2] = cvtpk(x1.x, x1.y); o[3] = cvtpk(x1.z, x1.w);
        *reinterpret_cast<u32x4*>(&k1b[tileo + (size_t)(s * 8 + (e8 ^ (s & 7))) * 8]) = o;

        x0 = *reinterpret_cast<const float4*>(k2 + g);
        x1 = *reinterpret_cast<const float4*>(k2 + g + 4);
        o[0] = cvtpk(x0.x, x0.y); o[1] = cvtpk(x0.z, x0.w);
        o[2] = cvtpk(x1.x, x1.y); o[3] = cvtpk(x1.z, x1.w);
        *reinterpret_cast<u32x4*>(&k2b[tileo + (size_t)(s * 8 + (e8 ^ (s & 7))) * 8]) = o;

        x0 = *reinterpret_cast<const float4*>(v1 + g);
        x1 = *reinterpret_cast<const float4*>(v1 + g + 4);
        o[0] = cvtpk(x0.x, x0.y); o[1] = cvtpk(x0.z, x0.w);
        o[2] = cvtpk(x1.x, x1.y); o[3] = cvtpk(x1.z, x1.w);
        *reinterpret_cast<u32x4*>(&vt[s * 80 + e8 * 8]) = o;   // row-major [s][d]
    }
    __syncthreads();

    #pragma unroll
    for (int it = 0; it < 2; ++it) {
        int u  = threadIdx.x + it * 256;
        int d  = u >> 3, sc8 = u & 7;
        u16x8 o;
        #pragma unroll
        for (int j = 0; j < 8; ++j) o[j] = vt[(sc8 * 8 + j) * 80 + d];  // column gather
        *reinterpret_cast<u16x8*>(&vb[tileo + (size_t)(d * 8 + sc8) * 8]) = o;  // [d][s] linear
    }
}

// ---------------------------------------------------------------------------
// Fused kernel. 4 waves = 2 q-subblocks x 2 s-halves; each wave: 32 q-rows
// (2 MFMA B-frags), half of each 64-s tile. K via double-buffered LDS
// (swizzled); V direct from L2; P redistributed via tiny per-wave LDS bounce.
// Partial accs (s-halves) merged through LDS at the end.
// ---------------------------------------------------------------------------
__global__ __launch_bounds__(256, 4) void fused_kernel(
    const float* __restrict__ q1, const float* __restrict__ q2,
    const unsigned short* __restrict__ k1b, const unsigned short* __restrict__ k2b,
    const unsigned short* __restrict__ vb, float* __restrict__ out)
{
    __shared__ unsigned short klds[2][2][4096];   // [buf][arr] 32 KiB
    __shared__ unsigned int   pbounce[4][256];    // per-wave 1 KiB bounce

    const int orig    = blockIdx.x;
    const int logical = (orig & 7) * 128 + (orig >> 3);   // XCD-chunked swizzle
    const int lblk = logical & 31;
    const int bh   = logical >> 5;
    const int b    = bh >> 4, h = bh & 15;

    const int tid  = threadIdx.x;
    const int w    = tid >> 6;
    const int lane = tid & 63;
    const int lr   = lane & 15;
    const int lg   = lane >> 4;
    const int qsub = w >> 1;       // 0,1 : which 32-q subblock
    const int sh   = w & 1;        // 0,1 : which 32-s half of each tile

    // ---- Q fragments, 2 q-groups, scale*log2e folded ----
    constexpr float C1 = 0.36067376022224085f;    // 2*(1/8)*log2(e)
    constexpr float C2 = -0.18033688011112043f;   // -(1/8)*log2(e)
    bf16x8 a1[2][2], a2[2][2];                    // [qg][es]
    #pragma unroll
    for (int qg = 0; qg < 2; ++qg) {
        const int    qrow  = lblk * 64 + qsub * 32 + qg * 16 + lr;
        const size_t qbase = ((size_t)((b * Lc + qrow) * Hc + h)) * Ec;
        #pragma unroll
        for (int es = 0; es < 2; ++es) {
            const float* p1 = q1 + qbase + es * 32 + lg * 8;
            const float* p2 = q2 + qbase + es * 32 + lg * 8;
            float4 x0 = *reinterpret_cast<const float4*>(p1);
            float4 x1 = *reinterpret_cast<const float4*>(p1 + 4);
            u32x4 o;
            o[0] = cvtpk(x0.x * C1, x0.y * C1); o[1] = cvtpk(x0.z * C1, x0.w * C1);
            o[2] = cvtpk(x1.x * C1, x1.y * C1); o[3] = cvtpk(x1.z * C1, x1.w * C1);
            a1[qg][es] = __builtin_bit_cast(bf16x8, o);
            x0 = *reinterpret_cast<const float4*>(p2);
            x1 = *reinterpret_cast<const float4*>(p2 + 4);
            o[0] = cvtpk(x0.x * C2, x0.y * C2); o[1] = cvtpk(x0.z * C2, x0.w * C2);
            o[2] = cvtpk(x1.x * C2, x1.y * C2); o[3] = cvtpk(x1.z * C2, x1.w * C2);
            a2[qg][es] = __builtin_bit_cast(bf16x8, o);
        }
    }

    f32x4 acc[2][4];                              // [qg][dt]
    #pragma unroll
    for (int qg = 0; qg < 2; ++qg)
        #pragma unroll
        for (int dt = 0; dt < 4; ++dt) acc[qg][dt] = (f32x4){0.f, 0.f, 0.f, 0.f};

    const unsigned short* k1g = k1b + (size_t)bh * TILES * TILE_ELEMS;
    const unsigned short* k2g = k2b + (size_t)bh * TILES * TILE_ELEMS;
    const unsigned short* vg  = vb  + (size_t)bh * TILES * TILE_ELEMS;
    unsigned int* pb = &pbounce[w][0];

    // stage tile 0 into buf 0 (2 x 16B per array per thread)
    {
        const size_t tb = (size_t)tid * 8;
        gl2lds16(k1g + tb,        &klds[0][0][tid * 8]);
        gl2lds16(k1g + tb + 2048, &klds[0][0][tid * 8 + 2048]);
        gl2lds16(k2g + tb,        &klds[0][1][tid * 8]);
        gl2lds16(k2g + tb + 2048, &klds[0][1][tid * 8 + 2048]);
    }

    int cur = 0;
    for (int st = 0; st < TILES; ++st) {
        __syncthreads();                           // drains prefetch; tile st ready
        if (st + 1 < TILES) {                      // issue next-tile prefetch now
            const size_t tb = (size_t)(st + 1) * TILE_ELEMS + tid * 8;
            const int nxt = cur ^ 1;
            gl2lds16(k1g + tb,        &klds[nxt][0][tid * 8]);
            gl2lds16(k1g + tb + 2048, &klds[nxt][0][tid * 8 + 2048]);
            gl2lds16(k2g + tb,        &klds[nxt][1][tid * 8]);
            gl2lds16(k2g + tb + 2048, &klds[nxt][1][tid * 8 + 2048]);
        }

        // ---- QK for both q-groups over this wave's s-half (2 ct slices) ----
        unsigned pq1[4];                           // qg1 packed P (kept in regs)
        #pragma unroll
        for (int c = 0; c < 2; ++c) {
            f32x4 s1[2] = {{0.f,0.f,0.f,0.f},{0.f,0.f,0.f,0.f}};
            f32x4 s2[2] = {{0.f,0.f,0.f,0.f},{0.f,0.f,0.f,0.f}};
            #pragma unroll
            for (int es = 0; es < 2; ++es) {
                const int off = ((sh * 2 + c) * 16 + lr) * 64 + (((4 * es + lg) ^ (lr & 7)) * 8);
                bf16x8 kb1 = __builtin_bit_cast(bf16x8, *reinterpret_cast<const u16x8*>(&klds[cur][0][off]));
                bf16x8 kb2 = __builtin_bit_cast(bf16x8, *reinterpret_cast<const u16x8*>(&klds[cur][1][off]));
                #pragma unroll
                for (int qg = 0; qg < 2; ++qg) {
                    s1[qg] = __builtin_amdgcn_mfma_f32_16x16x32_bf16(kb1, a1[qg][es], s1[qg], 0, 0, 0);
                    s2[qg] = __builtin_amdgcn_mfma_f32_16x16x32_bf16(kb2, a2[qg][es], s2[qg], 0, 0, 0);
                }
            }
            #pragma unroll
            for (int qg = 0; qg < 2; ++qg) {
                float p[4];
                #pragma unroll
                for (int i = 0; i < 4; ++i) {
                    float t  = fexp2(s1[qg][i]);
                    float uu = fexp2(s2[qg][i]);
                    p[i] = (t - 1.f) * __builtin_amdgcn_rcpf((t + 1.f) * (1.f + uu));
                }
                unsigned w0 = cvtpk(p[0], p[1]);
                unsigned w1 = cvtpk(p[2], p[3]);
                if (qg == 0) {
                    *reinterpret_cast<u32x2*>(&pb[(c * 4 + lg) * 32 + 2 * lr]) = (u32x2){w0, w1};
                } else {
                    pq1[c * 2] = w0; pq1[c * 2 + 1] = w1;
                }
            }
        }

        // ---- V fragments direct from L2 ([d][s] tiles) ----
        u16x8 vfr[4];
        #pragma unroll
        for (int dt = 0; dt < 4; ++dt)
            vfr[dt] = *reinterpret_cast<const u16x8*>(
                &vg[(size_t)st * TILE_ELEMS + (dt * 16 + lr) * 64 + sh * 32 + lg * 8]);

        // ---- PV qg0 ----
        asm volatile("" ::: "memory");
        u32x2 r0 = *reinterpret_cast<const u32x2*>(&pb[(2 * lg) * 32 + 2 * lr]);
        u32x2 r1 = *reinterpret_cast<const u32x2*>(&pb[(2 * lg + 1) * 32 + 2 * lr]);
        bf16x8 pa0 = __builtin_bit_cast(bf16x8, (u32x4){r0[0], r0[1], r1[0], r1[1]});
        #pragma unroll
        for (int dt = 0; dt < 4; ++dt)
            acc[0][dt] = __builtin_amdgcn_mfma_f32_16x16x32_bf16(
                pa0, __builtin_bit_cast(bf16x8, vfr[dt]), acc[0][dt], 0, 0, 0);

        // ---- PV qg1 (reuse same bounce region; same-wave LDS is in-order) ----
        asm volatile("" ::: "memory");
        *reinterpret_cast<u32x2*>(&pb[(lg) * 32 + 2 * lr])     = (u32x2){pq1[0], pq1[1]};
        *reinterpret_cast<u32x2*>(&pb[(4 + lg) * 32 + 2 * lr]) = (u32x2){pq1[2], pq1[3]};
        asm volatile("" ::: "memory");
        r0 = *reinterpret_cast<const u32x2*>(&pb[(2 * lg) * 32 + 2 * lr]);
        r1 = *reinterpret_cast<const u32x2*>(&pb[(2 * lg + 1) * 32 + 2 * lr]);
        bf16x8 pa1 = __builtin_bit_cast(bf16x8, (u32x4){r0[0], r0[1], r1[0], r1[1]});
        #pragma unroll
        for (int dt = 0; dt < 4; ++dt)
            acc[1][dt] = __builtin_amdgcn_mfma_f32_16x16x32_bf16(
                pa1, __builtin_bit_cast(bf16x8, vfr[dt]), acc[1][dt], 0, 0, 0);

        cur ^= 1;
    }

    // ---- merge s-halves + epilogue ----
    __syncthreads();
    float* mbuf = reinterpret_cast<float*>(&klds[0][0][0]);   // 16 KiB used
    if (sh == 1) {
        #pragma unroll
        for (int qg = 0; qg < 2; ++qg)
            #pragma unroll
            for (int dt = 0; dt < 4; ++dt)
                *reinterpret_cast<f32x4*>(&mbuf[(((qsub * 2 + qg) * 4 + dt) * 256) + lane * 4]) = acc[qg][dt];
    }
    __syncthreads();
    if (sh == 0) {
        #pragma unroll
        for (int qg = 0; qg < 2; ++qg) {
            const int orow = lblk * 64 + qsub * 32 + qg * 16;
            #pragma unroll
            for (int dt = 0; dt < 4; ++dt) {
                f32x4 o = *reinterpret_cast<const f32x4*>(&mbuf[(((qsub * 2 + qg) * 4 + dt) * 256) + lane * 4]);
                o += acc[qg][dt];
                #pragma unroll
                for (int i = 0; i < 4; ++i) {
                    int l = orow + lg * 4 + i;
                    out[((size_t)(b * Lc + l) * Hc + h) * Dc + dt * 16 + lr] = o[i];
                }
            }
        }
    }
}

// ---------------------------------------------------------------------------
// Fallback (round-1 kernel, proven correct) if ws_size is too small.
// ---------------------------------------------------------------------------
static __device__ __forceinline__ unsigned short f2bf(float f) {
    unsigned u = __builtin_bit_cast(unsigned, f);
    u += 0x7fffu + ((u >> 16) & 1u);
    return (unsigned short)(u >> 16);
}

__global__ __launch_bounds__(256) void fallback_kernel(
    const float* __restrict__ q1, const float* __restrict__ k1,
    const float* __restrict__ v1, const float* __restrict__ q2,
    const float* __restrict__ k2, float* __restrict__ out)
{
    constexpr int KSTR = 72, VSTR = 88, PSTR = 88;
    __shared__ unsigned short k1t[64 * KSTR];
    __shared__ unsigned short k2t[64 * KSTR];
    __shared__ unsigned short vtt[64 * VSTR];
    __shared__ unsigned short pt [4 * 16 * PSTR];

    const int blk  = blockIdx.x;
    const int lblk = blk & 31;
    const int bh   = blk >> 5;
    const int b    = bh >> 4;
    const int h    = bh & 15;
    const int tid  = threadIdx.x;
    const int w    = tid >> 6;
    const int lane = tid & 63;
    const int lr   = lane & 15;
    const int lg   = lane >> 4;

    const int    qrow  = lblk * 64 + w * 16 + lr;
    const size_t qbase = ((size_t)(b * Lc + qrow) * Hc + h) * Ec;
    bf16x8 a1[2], a2[2];
    for (int es = 0; es < 2; ++es) {
        u16x8 t1, t2;
        for (int j = 0; j < 8; ++j) {
            t1[j] = f2bf(q1[qbase + es * 32 + lg * 8 + j]);
            t2[j] = f2bf(q2[qbase + es * 32 + lg * 8 + j]);
        }
        a1[es] = __builtin_bit_cast(bf16x8, t1);
        a2[es] = __builtin_bit_cast(bf16x8, t2);
    }
    f32x4 acc[4];
    for (int i = 0; i < 4; ++i) acc[i] = (f32x4){0.f, 0.f, 0.f, 0.f};
    constexpr float CT = 0.25f, CS = -0.125f;

    for (int s0 = 0; s0 < Sc; s0 += 64) {
        for (int it = 0; it < 4; ++it) {
            int idx = tid + it * 256;
            int sr  = idx >> 4;
            int c4  = (idx & 15) << 2;
            size_t gk = ((size_t)(b * Sc + s0 + sr) * Hc + h) * Ec + c4;
            float4 x1 = *reinterpret_cast<const float4*>(k1 + gk);
            float4 x2 = *reinterpret_cast<const float4*>(k2 + gk);
            float4 xv = *reinterpret_cast<const float4*>(v1 + gk);
            u16x4 o1, o2;
            o1[0]=f2bf(x1.x); o1[1]=f2bf(x1.y); o1[2]=f2bf(x1.z); o1[3]=f2bf(x1.w);
            o2[0]=f2bf(x2.x); o2[1]=f2bf(x2.y); o2[2]=f2bf(x2.z); o2[3]=f2bf(x2.w);
            *reinterpret_cast<u16x4*>(&k1t[sr * KSTR + c4]) = o1;
            *reinterpret_cast<u16x4*>(&k2t[sr * KSTR + c4]) = o2;
            vtt[(c4 + 0) * VSTR + sr] = f2bf(xv.x);
            vtt[(c4 + 1) * VSTR + sr] = f2bf(xv.y);
            vtt[(c4 + 2) * VSTR + sr] = f2bf(xv.z);
            vtt[(c4 + 3) * VSTR + sr] = f2bf(xv.w);
        }
        __syncthreads();
        for (int ct = 0; ct < 4; ++ct) {
            f32x4 s1 = {0.f,0.f,0.f,0.f}, s2 = {0.f,0.f,0.f,0.f};
            for (int es = 0; es < 2; ++es) {
                bf16x8 b1 = __builtin_bit_cast(bf16x8,
                    *reinterpret_cast<const u16x8*>(&k1t[(ct*16 + lr) * KSTR + es*32 + lg*8]));
                bf16x8 b2 = __builtin_bit_cast(bf16x8,
                    *reinterpret_cast<const u16x8*>(&k2t[(ct*16 + lr) * KSTR + es*32 + lg*8]));
                s1 = __builtin_amdgcn_mfma_f32_16x16x32_bf16(a1[es], b1, s1, 0, 0, 0);
                s2 = __builtin_amdgcn_mfma_f32_16x16x32_bf16(a2[es], b2, s2, 0, 0, 0);
            }
            for (int i = 0; i < 4; ++i) {
                float xa = fminf(fmaxf(s1[i] * CT, -30.f), 30.f);
                float xb = fminf(fmaxf(s2[i] * CS, -30.f), 30.f);
                float t  = __expf(xa);
                float u  = __expf(xb);
                float p  = (t - 1.f) * __builtin_amdgcn_rcpf((t + 1.f) * (1.f + u));
                pt[(w*16 + lg*4 + i) * PSTR + ct*16 + lr] = f2bf(p);
            }
        }
        asm volatile("s_waitcnt lgkmcnt(0)" ::: "memory");
        for (int ks = 0; ks < 2; ++ks) {
            bf16x8 pa = __builtin_bit_cast(bf16x8,
                *reinterpret_cast<const u16x8*>(&pt[(w*16 + lr) * PSTR + ks*32 + lg*8]));
            for (int dt = 0; dt < 4; ++dt) {
                bf16x8 vf = __builtin_bit_cast(bf16x8,
                    *reinterpret_cast<const u16x8*>(&vtt[(dt*16 + lr) * VSTR + ks*32 + lg*8]));
                acc[dt] = __builtin_amdgcn_mfma_f32_16x16x32_bf16(pa, vf, acc[dt], 0, 0, 0);
            }
        }
        __syncthreads();
    }
    const int orow = lblk * 64 + w * 16;
    for (int dt = 0; dt < 4; ++dt)
        for (int i = 0; i < 4; ++i) {
            int l = orow + lg * 4 + i;
            out[((size_t)(b * Lc + l) * Hc + h) * Dc + dt * 16 + lr] = acc[dt][i];
        }
}

extern "C" void kernel_launch(void* const* d_in, const int* in_sizes, int n_in,
                              void* d_out, int out_size, void* d_ws, size_t ws_size,
                              hipStream_t stream) {
    const float* q1 = (const float*)d_in[0];
    const float* k1 = (const float*)d_in[1];
    const float* v1 = (const float*)d_in[2];
    const float* q2 = (const float*)d_in[3];
    const float* k2 = (const float*)d_in[4];
    float* out = (float*)d_out;

    if (ws_size >= WS_NEED) {
        unsigned short* k1b = (unsigned short*)d_ws;
        unsigned short* k2b = k1b + ARR_ELEMS;
        unsigned short* vbp = k2b + ARR_ELEMS;
        prepass_kernel<<<dim3(NBH * TILES), dim3(256), 0, stream>>>(k1, k2, v1, k1b, k2b, vbp);
        fused_kernel<<<dim3(NBH * TILES), dim3(256), 0, stream>>>(q1, q2, k1b, k2b, vbp, out);
    } else {
        fallback_kernel<<<dim3(NBH * TILES), dim3(256), 0, stream>>>(q1, k1, v1, q2, k2, out);
    }
}